// Round 4
// baseline (79.843 us; speedup 1.0000x reference)
//
#include <hip/hip_runtime.h>

#define VOCAB 512
#define W 24
#define WPB 4             // waves per block (256 threads)
#define RPW 4             // rows per wave (32768 rows / 8192 waves)

typedef float f32x4 __attribute__((ext_vector_type(4)));  // native vec: ok for nontemporal builtins

__global__ __launch_bounds__(256, 8) void fofe_kernel(
    const int*   __restrict__ sents,    // [nrows * W] int32 char ids (0 = pad)
    const int*   __restrict__ lengths,  // [nlen]
    const float* __restrict__ alpha_p,  // [1]
    float*       __restrict__ out,      // [nrows*VOCAB] ++ [nlen] lengths-as-f32
    int nrows, int nlen)
{
    // Two wave-private 512-float histograms per wave -> 16 KB/block.
    // 8 blocks/CU * 16 KB = 128 KB <= 160 KB, full 32-wave/CU residency.
    __shared__ float lds[WPB][2][VOCAB];

    const int wave  = threadIdx.x >> 6;
    const int lane  = threadIdx.x & 63;
    const int gwave = blockIdx.x * WPB + wave;
    const int nw    = gridDim.x * WPB;

    if (blockIdx.x == 0 && threadIdx.x < nlen) {
        out[(size_t)nrows * VOCAB + threadIdx.x] = (float)lengths[threadIdx.x];
    }

    const float alpha = alpha_p[0];

    // ---- phase 1: issue ALL row loads up-front (independent, coalesced) ----
    int rows[RPW];
    int c[RPW];
    #pragma unroll
    for (int k = 0; k < RPW; ++k) {
        rows[k] = gwave + k * nw;
        c[k] = 0;
        if (rows[k] < nrows && lane < W)
            c[k] = sents[(size_t)rows[k] * W + lane];
    }

    // ---- phase 2: decay weights for every row (no memory ops) ----
    float w[RPW];
    #pragma unroll
    for (int k = 0; k < RPW; ++k) {
        unsigned long long mask = __ballot(c[k] != 0);
        int suffix = __popcll(mask >> ((lane + 1) & 63)); // meaningful for lane<24
        float acc = 1.0f, p = alpha;
        #pragma unroll
        for (int b = 0; b < 5; ++b) { if (suffix & (1 << b)) acc *= p; p *= p; }
        w[k] = acc;                                       // unused where c==0
    }

    f32x4* b04 = (f32x4*)lds[wave][0];
    f32x4* b14 = (f32x4*)lds[wave][1];
    float* b0  = (float*)b04;
    float* b1  = (float*)b14;

    // ---- phase 3: scatter + dump, two rows per drain ----
    #pragma unroll
    for (int pair = 0; pair < RPW / 2; ++pair) {
        const int k0 = 2 * pair, k1 = 2 * pair + 1;
        const f32x4 z = (f32x4)(0.f);
        b04[lane] = z; b04[lane + 64] = z;               // ds_write_b128 x2
        b14[lane] = z; b14[lane + 64] = z;
        // same-wave DS pipe is in-order: zeros land before the adds
        if (c[k0] != 0) atomicAdd(&b0[c[k0]], w[k0]);    // ds_add_f32
        if (c[k1] != 0) atomicAdd(&b1[c[k1]], w[k1]);
        asm volatile("s_waitcnt lgkmcnt(0)" ::: "memory");

        if (rows[k0] < nrows) {
            f32x4* o = (f32x4*)(out + (size_t)rows[k0] * VOCAB);
            __builtin_nontemporal_store(b04[lane],      &o[lane]);
            __builtin_nontemporal_store(b04[lane + 64], &o[lane + 64]);
        }
        if (rows[k1] < nrows) {
            f32x4* o = (f32x4*)(out + (size_t)rows[k1] * VOCAB);
            __builtin_nontemporal_store(b14[lane],      &o[lane]);
            __builtin_nontemporal_store(b14[lane + 64], &o[lane + 64]);
        }
    }
}

extern "C" void kernel_launch(void* const* d_in, const int* in_sizes, int n_in,
                              void* d_out, int out_size, void* d_ws, size_t ws_size,
                              hipStream_t stream) {
    const int*   sents   = (const int*)d_in[0];
    const int*   lengths = (const int*)d_in[1];
    const float* alpha   = (const float*)d_in[2];
    float*       out     = (float*)d_out;

    const int nrows = in_sizes[0] / W;   // 32768
    const int nlen  = in_sizes[1];       // 64

    // 2048 blocks * 4 waves * 4 rows = 32768 rows exactly
    int blocks = (nrows + WPB * RPW - 1) / (WPB * RPW);
    fofe_kernel<<<blocks, 256, 0, stream>>>(sents, lengths, alpha, out, nrows, nlen);
}